// Round 5
// baseline (214.164 us; speedup 1.0000x reference)
//
#include <hip/hip_runtime.h>
#include <hip/hip_bf16.h>
#include <math.h>

#define D_CH   256
#define NHEAD  4
#define DHEAD  64
#define NPTS   4096
#define KSPLIT 8
#define KCHUNK (NPTS / KSPLIT)
#define BN_RSQ 0.99999500003749963f   // 1/sqrt(1 + 1e-5)

typedef __attribute__((ext_vector_type(4))) float f32x4;
typedef __attribute__((ext_vector_type(8))) short bf16x8;
typedef unsigned short ushort_t;

__device__ __forceinline__ ushort_t f2bf(float x) {
    unsigned int b = __float_as_uint(x);
    return (ushort_t)((b + 0x7FFF + ((b >> 16) & 1)) >> 16);  // RNE
}
__device__ __forceinline__ float bf2f(ushort_t u) {
    return __uint_as_float(((unsigned int)u) << 16);
}
__device__ __forceinline__ unsigned pack2bf(float lo, float hi) {
    return (unsigned)f2bf(lo) | ((unsigned)f2bf(hi) << 16);
}

// ---------------------------------------------------------------------------
// prep: transpose-cast x [256][4096] f32 -> xT [4096][256] bf16
// ---------------------------------------------------------------------------
__global__ __launch_bounds__(256) void transpose_cast(
    const float* __restrict__ x, ushort_t* __restrict__ xT)
{
    __shared__ float xs[64][65];
    const int tid = threadIdx.x;
    const int n0 = blockIdx.x * 64, k0 = blockIdx.y * 64;
#pragma unroll
    for (int p = 0; p < 16; ++p) {
        int kk = p * 4 + (tid >> 6), nn = tid & 63;
        xs[kk][nn] = x[(size_t)(k0 + kk) * NPTS + n0 + nn];
    }
    __syncthreads();
#pragma unroll
    for (int p = 0; p < 16; ++p) {
        int nn = p * 4 + (tid >> 6), kk = tid & 63;
        xT[(size_t)(n0 + nn) * D_CH + k0 + kk] = f2bf(xs[kk][nn]);
    }
}

// ---------------------------------------------------------------------------
// Shared MFMA GEMM tile body: acc[2][2] = sum_k A[m][k]*Bt[n][k]
// ---------------------------------------------------------------------------
__device__ __forceinline__ void gemm_tile_body(
    const float* __restrict__ A, const ushort_t* __restrict__ Bt,
    int K, int m0, int n0, int l15, int lhi, f32x4 acc[2][2])
{
#pragma unroll
    for (int i = 0; i < 2; ++i)
#pragma unroll
        for (int j = 0; j < 2; ++j) acc[i][j] = (f32x4){0.f, 0.f, 0.f, 0.f};

    for (int k0 = 0; k0 < K; k0 += 32) {
        bf16x8 af[2], bfr[2];
#pragma unroll
        for (int mf = 0; mf < 2; ++mf) {
            const float* ap = A + (size_t)(m0 + mf * 16 + l15) * K + k0 + lhi * 8;
            float4 a0 = *(const float4*)ap;
            float4 a1 = *(const float4*)(ap + 4);
            bf16x8 t;
            t[0] = (short)f2bf(a0.x); t[1] = (short)f2bf(a0.y);
            t[2] = (short)f2bf(a0.z); t[3] = (short)f2bf(a0.w);
            t[4] = (short)f2bf(a1.x); t[5] = (short)f2bf(a1.y);
            t[6] = (short)f2bf(a1.z); t[7] = (short)f2bf(a1.w);
            af[mf] = t;
        }
#pragma unroll
        for (int nf = 0; nf < 2; ++nf)
            bfr[nf] = *(const bf16x8*)&Bt[(size_t)(n0 + nf * 16 + l15) * K + k0 + lhi * 8];
#pragma unroll
        for (int mf = 0; mf < 2; ++mf)
#pragma unroll
            for (int nf = 0; nf < 2; ++nf)
                acc[mf][nf] = __builtin_amdgcn_mfma_f32_16x16x32_bf16(af[mf], bfr[nf], acc[mf][nf], 0, 0, 0);
    }
}

// ---------------------------------------------------------------------------
// Fused QKV projection: z selects {Wq->Qt, Wk->Kt, Wv->Vt}.
// ---------------------------------------------------------------------------
__global__ __launch_bounds__(256) void gemm_qkv(
    const float* __restrict__ Wq, const float* __restrict__ bq,
    const float* __restrict__ Wk, const float* __restrict__ bk,
    const float* __restrict__ Wv, const float* __restrict__ bv,
    const ushort_t* __restrict__ xT,
    ushort_t* __restrict__ Qt, ushort_t* __restrict__ Kt, ushort_t* __restrict__ Vt)
{
    const int tid = threadIdx.x;
    const int w = tid >> 6, lane = tid & 63, l15 = lane & 15, lhi = lane >> 4;
    const int wm = w >> 1, wn = w & 1;
    const int m0 = blockIdx.y * 64 + wm * 32;
    const int n0 = blockIdx.x * 64 + wn * 32;
    const int z = blockIdx.z;

    const float* A    = (z == 0) ? Wq : (z == 1) ? Wk : Wv;
    const float* bias = (z == 0) ? bq : (z == 1) ? bk : bv;
    ushort_t* dst     = (z == 0) ? Qt : (z == 1) ? Kt : Vt;

    f32x4 acc[2][2];
    gemm_tile_body(A, xT, D_CH, m0, n0, l15, lhi, acc);

#pragma unroll
    for (int mf = 0; mf < 2; ++mf) {
#pragma unroll
        for (int r = 0; r < 4; ++r) {
            int m = m0 + mf * 16 + lhi * 4 + r;
            float bi = bias[m];
#pragma unroll
            for (int nf = 0; nf < 2; ++nf) {
                int n = n0 + nf * 16 + l15;
                float v = acc[mf][nf][r] + bi;
                if (z < 2) dst[((size_t)(m >> 6) * NPTS + n) * 64 + (m & 63)] = f2bf(v);
                else       dst[(size_t)m * NPTS + n] = f2bf(v);
            }
        }
    }
}

// ---------------------------------------------------------------------------
// Generic MFMA GEMM for the MLP chain.
// out_mode: 0 = f32 C[m][n] (+resid);  3 = bf16 transposed Cu[n*M + m]
// ---------------------------------------------------------------------------
__global__ __launch_bounds__(256) void gemm_mfma(
    const float* __restrict__ A, const ushort_t* __restrict__ Bt,
    void* __restrict__ Cout, int M, int N, int K,
    const float* __restrict__ bias, const float* __restrict__ gamma,
    const float* __restrict__ beta, int relu, const float* __restrict__ resid,
    int out_mode)
{
    const int tid = threadIdx.x;
    const int w = tid >> 6, lane = tid & 63, l15 = lane & 15, lhi = lane >> 4;
    const int wm = w >> 1, wn = w & 1;
    const int m0 = blockIdx.y * 64 + wm * 32;
    const int n0 = blockIdx.x * 64 + wn * 32;

    f32x4 acc[2][2];
    gemm_tile_body(A, Bt, K, m0, n0, l15, lhi, acc);

    float* Cf = (float*)Cout;
    ushort_t* Cu = (ushort_t*)Cout;
#pragma unroll
    for (int mf = 0; mf < 2; ++mf) {
#pragma unroll
        for (int r = 0; r < 4; ++r) {
            int m = m0 + mf * 16 + lhi * 4 + r;
            float bi = bias[m];
            float sc = 1.0f, sh = 0.0f;
            if (gamma) { sc = gamma[m] * BN_RSQ; sh = beta[m]; }
#pragma unroll
            for (int nf = 0; nf < 2; ++nf) {
                int n = n0 + nf * 16 + l15;
                float v = acc[mf][nf][r] + bi;
                if (gamma) v = v * sc + sh;
                if (relu)  v = fmaxf(v, 0.0f);
                if (resid) v += resid[(size_t)m * N + n];
                if (out_mode == 0) Cf[(size_t)m * N + n] = v;
                else               Cu[(size_t)n * M + m] = f2bf(v);
            }
        }
    }
}

// ---------------------------------------------------------------------------
// One 64-key attention tile (swapped-operand). Consumes scur (S mask for
// tile k0, loaded one phase earlier); issues loads for tile knext into snxt.
// ---------------------------------------------------------------------------
__device__ __forceinline__ void attn_tile(
    int k0, int knext, const float* __restrict__ Srow,
    const ushort_t* __restrict__ Kh, const ushort_t* __restrict__ Vh,
    const bf16x8& qf0, const bf16x8& qf1,
    f32x4 (&scur)[4], f32x4 (&snxt)[4], f32x4 (&macc)[4],
    float& mrun, float& lrun,
    ushort_t (* __restrict__ Pw)[72], int l15, int lhi)
{
    // issue next tile's S loads first (full phase of latency cover)
#pragma unroll
    for (int kb = 0; kb < 4; ++kb)
        snxt[kb] = *(const f32x4*)&Srow[knext + kb * 16 + lhi * 4];

    // QK^T swapped: sacc[kb][r] = score[key=kb*16+lhi*4+r][q=l15]
    f32x4 sacc[4];
#pragma unroll
    for (int kb = 0; kb < 4; ++kb) {
        const ushort_t* kp = Kh + (size_t)(k0 + kb * 16 + l15) * DHEAD + lhi * 8;
        bf16x8 kf0 = *(const bf16x8*)kp;
        bf16x8 kf1 = *(const bf16x8*)(kp + 32);
        f32x4 z = (f32x4){0.f, 0.f, 0.f, 0.f};
        z = __builtin_amdgcn_mfma_f32_16x16x32_bf16(kf0, qf0, z, 0, 0, 0);
        z = __builtin_amdgcn_mfma_f32_16x16x32_bf16(kf1, qf1, z, 0, 0, 0);
        sacc[kb] = z;
    }

    // mask*scale; per-lane softmax over the tile's 64 keys
    float p_[4][4];
    float tmax = -3.0e38f;
#pragma unroll
    for (int kb = 0; kb < 4; ++kb)
#pragma unroll
        for (int r = 0; r < 4; ++r) {
            float sv = sacc[kb][r] * 0.125f * scur[kb][r];
            p_[kb][r] = sv;
            tmax = fmaxf(tmax, sv);
        }
    tmax = fmaxf(tmax, __shfl_xor(tmax, 16));
    tmax = fmaxf(tmax, __shfl_xor(tmax, 32));
    float mn = fmaxf(mrun, tmax);
    float cf = __expf(mrun - mn);
    mrun = mn;
    float tsum = 0.0f;
#pragma unroll
    for (int kb = 0; kb < 4; ++kb)
#pragma unroll
        for (int r = 0; r < 4; ++r) {
            p_[kb][r] = __expf(p_[kb][r] - mn);
            tsum += p_[kb][r];
        }
    tsum += __shfl_xor(tsum, 16);
    tsum += __shfl_xor(tsum, 32);
    lrun = lrun * cf + tsum;
#pragma unroll
    for (int db = 0; db < 4; ++db)
#pragma unroll
        for (int r = 0; r < 4; ++r) macc[db][r] *= cf;

    // P -> bf16 packed -> per-warp LDS [q][key]
#pragma unroll
    for (int kb = 0; kb < 4; ++kb) {
        *(unsigned*)&Pw[l15][kb * 16 + lhi * 4]     = pack2bf(p_[kb][0], p_[kb][1]);
        *(unsigned*)&Pw[l15][kb * 16 + lhi * 4 + 2] = pack2bf(p_[kb][2], p_[kb][3]);
    }
    // same-wave RAW through LDS; compiler inserts lgkmcnt wait

    // PV: mfma(A=V row=d, B=P col=q), 2 key-halves x 4 d-blocks
#pragma unroll
    for (int m = 0; m < 2; ++m) {
        bf16x8 pf = *(const bf16x8*)&Pw[l15][m * 32 + lhi * 8];
#pragma unroll
        for (int db = 0; db < 4; ++db) {
            const ushort_t* vp = Vh + (size_t)(db * 16 + l15) * NPTS
                               + k0 + m * 32 + lhi * 8;
            bf16x8 vf = *(const bf16x8*)vp;
            macc[db] = __builtin_amdgcn_mfma_f32_16x16x32_bf16(vf, pf, macc[db], 0, 0, 0);
        }
    }
}

// ---------------------------------------------------------------------------
// MFMA flash attention, key-split 8, 2-phase software-pipelined S stream.
// Block = (qtile 64, head, ksplit); 4 warps x 16 queries.
// ---------------------------------------------------------------------------
__global__ __launch_bounds__(256, 4) void attn_mfma(
    const ushort_t* __restrict__ Qt, const ushort_t* __restrict__ Kt,
    const ushort_t* __restrict__ Vt, const float* __restrict__ S,
    ushort_t* __restrict__ pacc, float* __restrict__ pm, float* __restrict__ pl)
{
    __shared__ __align__(16) ushort_t P_lds[4][16][72];

    const int tid  = threadIdx.x;
    const int w    = tid >> 6;
    const int lane = tid & 63;
    const int l15  = lane & 15;
    const int lhi  = lane >> 4;
    const int h    = blockIdx.y;
    const int ks   = blockIdx.z;
    const int q0   = blockIdx.x * 64 + w * 16;
    const int kbase = ks * KCHUNK, kend = kbase + KCHUNK;

    const ushort_t* Kh = Kt + (size_t)h * NPTS * DHEAD;
    const ushort_t* Vh = Vt + (size_t)h * DHEAD * NPTS;
    const float* Srow = S + (size_t)(q0 + l15) * NPTS;
    ushort_t (* __restrict__ Pw)[72] = P_lds[w];

    bf16x8 qf0, qf1;
    {
        const ushort_t* qp = Qt + ((size_t)h * NPTS + q0 + l15) * DHEAD + lhi * 8;
        qf0 = *(const bf16x8*)qp;
        qf1 = *(const bf16x8*)(qp + 32);
    }

    f32x4 macc[4];
#pragma unroll
    for (int db = 0; db < 4; ++db) macc[db] = (f32x4){0.f, 0.f, 0.f, 0.f};
    float mrun = -3.0e38f, lrun = 0.0f;

    // preload S tile 0 into sA
    f32x4 sA[4], sB[4];
#pragma unroll
    for (int kb = 0; kb < 4; ++kb)
        sA[kb] = *(const f32x4*)&Srow[kbase + kb * 16 + lhi * 4];

    // KCHUNK=512 -> 4 pair-iterations of 2 tiles (static A/B phases)
    for (int k0 = kbase; k0 < kend; k0 += 128) {
        const int kn1 = k0 + 64;
        const int kn2 = (k0 + 128 < kend) ? k0 + 128 : kbase;
        attn_tile(k0,  kn1, Srow, Kh, Vh, qf0, qf1, sA, sB, macc, mrun, lrun, Pw, l15, lhi);
        attn_tile(kn1, kn2, Srow, Kh, Vh, qf0, qf1, sB, sA, macc, mrun, lrun, Pw, l15, lhi);
    }

    // store unnormalized partials
    const size_t pb = ((size_t)ks * NHEAD + h) * NPTS;
    ushort_t* prow = pacc + (pb + q0 + l15) * DHEAD;
#pragma unroll
    for (int db = 0; db < 4; ++db) {
        *(unsigned*)&prow[db * 16 + lhi * 4]     = pack2bf(macc[db][0], macc[db][1]);
        *(unsigned*)&prow[db * 16 + lhi * 4 + 2] = pack2bf(macc[db][2], macc[db][3]);
    }
    if (lane < 16) {
        pm[pb + q0 + lane] = mrun;
        pl[pb + q0 + lane] = lrun;
    }
}

// ---------------------------------------------------------------------------
// Merge KSPLIT partials -> msgT [N][256] bf16.
// ---------------------------------------------------------------------------
__global__ __launch_bounds__(256) void attn_merge(
    const ushort_t* __restrict__ pacc, const float* __restrict__ pm,
    const float* __restrict__ pl, ushort_t* __restrict__ msgT)
{
    const int h = blockIdx.y;
    const int q = blockIdx.x * 64 + (threadIdx.x >> 2);
    const int d0 = (threadIdx.x & 3) * 16;

    float m[KSPLIT], l[KSPLIT];
#pragma unroll
    for (int ks = 0; ks < KSPLIT; ++ks) {
        size_t pb = ((size_t)ks * NHEAD + h) * NPTS + q;
        m[ks] = pm[pb];
        l[ks] = pl[pb];
    }
    float ms = m[0];
#pragma unroll
    for (int ks = 1; ks < KSPLIT; ++ks) ms = fmaxf(ms, m[ks]);
    float wgt[KSPLIT], ls = 0.0f;
#pragma unroll
    for (int ks = 0; ks < KSPLIT; ++ks) {
        wgt[ks] = __expf(m[ks] - ms);
        ls += wgt[ks] * l[ks];
    }
    float inv = 1.0f / ls;

    float out[16];
#pragma unroll
    for (int j = 0; j < 16; ++j) out[j] = 0.0f;
#pragma unroll
    for (int ks = 0; ks < KSPLIT; ++ks) {
        const ushort_t* ap = pacc + (((size_t)ks * NHEAD + h) * NPTS + q) * DHEAD + d0;
        bf16x8 v0 = *(const bf16x8*)ap;
        bf16x8 v1 = *(const bf16x8*)(ap + 8);
#pragma unroll
        for (int j = 0; j < 8; ++j) {
            out[j]     += wgt[ks] * bf2f((ushort_t)v0[j]);
            out[8 + j] += wgt[ks] * bf2f((ushort_t)v1[j]);
        }
    }
    bf16x8 o0, o1;
#pragma unroll
    for (int j = 0; j < 8; ++j) {
        o0[j] = (short)f2bf(out[j] * inv);
        o1[j] = (short)f2bf(out[8 + j] * inv);
    }
    ushort_t* op = msgT + (size_t)q * D_CH + h * DHEAD + d0;
    *(bf16x8*)op = o0;
    *(bf16x8*)(op + 8) = o1;
}

// ---------------------------------------------------------------------------
extern "C" void kernel_launch(void* const* d_in, const int* in_sizes, int n_in,
                              void* d_out, int out_size, void* d_ws, size_t ws_size,
                              hipStream_t stream) {
    const float* x  = (const float*)d_in[0];
    const float* S  = (const float*)d_in[1];
    const float* Wq = (const float*)d_in[2];
    const float* bq = (const float*)d_in[3];
    const float* Wk = (const float*)d_in[4];
    const float* bk = (const float*)d_in[5];
    const float* Wv = (const float*)d_in[6];
    const float* bv = (const float*)d_in[7];
    const float* W1 = (const float*)d_in[8];
    const float* b1 = (const float*)d_in[9];
    const float* g1 = (const float*)d_in[10];
    const float* be1= (const float*)d_in[11];
    const float* W2 = (const float*)d_in[12];
    const float* b2 = (const float*)d_in[13];
    const float* g2 = (const float*)d_in[14];
    const float* be2= (const float*)d_in[15];
    const float* W3 = (const float*)d_in[16];
    const float* b3 = (const float*)d_in[17];

    char* ws = (char*)d_ws;
    const size_t MB = 1024 * 1024;
    // xT (0-2MB) is dead after gemm_qkv; msgT reuses it (rewritten every call)
    ushort_t* xT   = (ushort_t*)(ws);                       // [4096][256] bf16, 2 MB
    ushort_t* msgT = (ushort_t*)(ws);                       // [4096][256] bf16, 2 MB
    ushort_t* Qt   = (ushort_t*)(ws + 2 * MB);              // [4][4096][64] bf16
    ushort_t* Kt   = (ushort_t*)(ws + 4 * MB);
    ushort_t* Vt   = (ushort_t*)(ws + 6 * MB);              // [4][64][4096] bf16
    ushort_t* pacc = (ushort_t*)(ws + 8 * MB);              // [8][4][4096][64] bf16, 16 MB
    float*    pm   = (float*)   (ws + 24 * MB);             // 512 KB
    float*    pl   = (float*)   (ws + 24 * MB + 524288);    // 512 KB
    ushort_t* h1T  = (ushort_t*)(ws + 25 * MB);             // [4096][128] bf16, 1 MB
    ushort_t* h2T  = (ushort_t*)(ws + 26 * MB);             // [4096][128] bf16, 1 MB

    transpose_cast<<<dim3(64, 4), 256, 0, stream>>>(x, xT);
    gemm_qkv<<<dim3(64, 4, 3), 256, 0, stream>>>(Wq, bq, Wk, bk, Wv, bv, xT, Qt, Kt, Vt);

    attn_mfma<<<dim3(64, NHEAD, KSPLIT), 256, 0, stream>>>(Qt, Kt, Vt, S, pacc, pm, pl);
    attn_merge<<<dim3(64, NHEAD), 256, 0, stream>>>(pacc, pm, pl, msgT);

    gemm_mfma<<<dim3(64, 2), 256, 0, stream>>>(W1, msgT, h1T, 128, NPTS, 256, b1, g1, be1, 1, nullptr, 3);
    gemm_mfma<<<dim3(64, 2), 256, 0, stream>>>(W2, h1T, h2T, 128, NPTS, 128, b2, g2, be2, 1, nullptr, 3);
    gemm_mfma<<<dim3(64, 4), 256, 0, stream>>>(W3, h2T, d_out, 256, NPTS, 128, b3, nullptr, nullptr, 0, x, 0);
}

// Round 6
// 144.368 us; speedup vs baseline: 1.4835x; 1.4835x over previous
//
#include <hip/hip_runtime.h>
#include <hip/hip_bf16.h>
#include <math.h>

#define D_CH   256
#define NHEAD  4
#define DHEAD  64
#define NPTS   4096
#define KSPLIT 8
#define KCHUNK (NPTS / KSPLIT)
#define BN_RSQ 0.99999500003749963f   // 1/sqrt(1 + 1e-5)
#define HSTRIDE 262144                // 4096*64 ushorts per head

typedef __attribute__((ext_vector_type(4))) float f32x4;
typedef __attribute__((ext_vector_type(8))) short bf16x8;
typedef unsigned short ushort_t;

__device__ __forceinline__ ushort_t f2bf(float x) {
    unsigned int b = __float_as_uint(x);
    return (ushort_t)((b + 0x7FFF + ((b >> 16) & 1)) >> 16);  // RNE
}
__device__ __forceinline__ float bf2f(ushort_t u) {
    return __uint_as_float(((unsigned int)u) << 16);
}
__device__ __forceinline__ unsigned pack2bf(float lo, float hi) {
    return (unsigned)f2bf(lo) | ((unsigned)f2bf(hi) << 16);
}

// ---------------------------------------------------------------------------
// prep: transpose-cast x [256][4096] f32 -> xT [4096][256] bf16
// ---------------------------------------------------------------------------
__global__ __launch_bounds__(256) void transpose_cast(
    const float* __restrict__ x, ushort_t* __restrict__ xT)
{
    __shared__ float xs[64][65];
    const int tid = threadIdx.x;
    const int n0 = blockIdx.x * 64, k0 = blockIdx.y * 64;
#pragma unroll
    for (int p = 0; p < 16; ++p) {
        int kk = p * 4 + (tid >> 6), nn = tid & 63;
        xs[kk][nn] = x[(size_t)(k0 + kk) * NPTS + n0 + nn];
    }
    __syncthreads();
#pragma unroll
    for (int p = 0; p < 16; ++p) {
        int nn = p * 4 + (tid >> 6), kk = tid & 63;
        xT[(size_t)(n0 + nn) * D_CH + k0 + kk] = f2bf(xs[kk][nn]);
    }
}

// ---------------------------------------------------------------------------
// prep: S [4096][4096] f32 -> Sf tile-major fragment layout (f32, 64 MB):
//   Sf[(qt*64+kt)*4096 + w*1024 + kb*256 + lane*4 + r]
//     = S[qt*64 + w*16 + (lane&15)][kt*64 + kb*16 + (lane>>4)*4 + r]
// Both global read and global write coalesced; permutation via LDS.
// ---------------------------------------------------------------------------
__global__ __launch_bounds__(256) void prep_mask(
    const float* __restrict__ S, float* __restrict__ Sf)
{
    __shared__ float lds[64][68];
    const int tid = threadIdx.x;
    const int qt = blockIdx.x, kt = blockIdx.y;
    const float* Sblk = S + (size_t)qt * 64 * NPTS + kt * 64;

#pragma unroll
    for (int p = 0; p < 4; ++p) {
        int slot = p * 256 + tid;
        int row = slot >> 4, col4 = slot & 15;
        f32x4 v = *(const f32x4*)&Sblk[(size_t)row * NPTS + col4 * 4];
        *(f32x4*)&lds[row][col4 * 4] = v;
    }
    __syncthreads();

    float* dst = Sf + ((size_t)qt * 64 + kt) * 4096;
#pragma unroll
    for (int p = 0; p < 4; ++p) {
        int q_rel = p * 16 + (tid & 15);
        int k_rel = (tid >> 6) * 16 + ((tid >> 4) & 3) * 4;
        f32x4 v = *(const f32x4*)&lds[q_rel][k_rel];
        *(f32x4*)&dst[p * 1024 + tid * 4] = v;
    }
}

// ---------------------------------------------------------------------------
// Shared MFMA GEMM tile body: acc[2][2] = sum_k A[m][k]*Bt[n][k]
// ---------------------------------------------------------------------------
__device__ __forceinline__ void gemm_tile_body(
    const float* __restrict__ A, const ushort_t* __restrict__ Bt,
    int K, int m0, int n0, int l15, int lhi, f32x4 acc[2][2])
{
#pragma unroll
    for (int i = 0; i < 2; ++i)
#pragma unroll
        for (int j = 0; j < 2; ++j) acc[i][j] = (f32x4){0.f, 0.f, 0.f, 0.f};

    for (int k0 = 0; k0 < K; k0 += 32) {
        bf16x8 af[2], bfr[2];
#pragma unroll
        for (int mf = 0; mf < 2; ++mf) {
            const float* ap = A + (size_t)(m0 + mf * 16 + l15) * K + k0 + lhi * 8;
            float4 a0 = *(const float4*)ap;
            float4 a1 = *(const float4*)(ap + 4);
            bf16x8 t;
            t[0] = (short)f2bf(a0.x); t[1] = (short)f2bf(a0.y);
            t[2] = (short)f2bf(a0.z); t[3] = (short)f2bf(a0.w);
            t[4] = (short)f2bf(a1.x); t[5] = (short)f2bf(a1.y);
            t[6] = (short)f2bf(a1.z); t[7] = (short)f2bf(a1.w);
            af[mf] = t;
        }
#pragma unroll
        for (int nf = 0; nf < 2; ++nf)
            bfr[nf] = *(const bf16x8*)&Bt[(size_t)(n0 + nf * 16 + l15) * K + k0 + lhi * 8];
#pragma unroll
        for (int mf = 0; mf < 2; ++mf)
#pragma unroll
            for (int nf = 0; nf < 2; ++nf)
                acc[mf][nf] = __builtin_amdgcn_mfma_f32_16x16x32_bf16(af[mf], bfr[nf], acc[mf][nf], 0, 0, 0);
    }
}

// ---------------------------------------------------------------------------
// Fused QKV projection -> fragment-major layouts.
//  Qf/Kf (frag16): idx = h*HSTRIDE + (n>>4)*1024 + (d>>5)*512
//                       + (((d>>3)&3)*16 + (n&15))*8 + (d&7)
//  Vf:             idx = h*HSTRIDE + (n>>6)*4096 + (d>>4)*1024
//                       + ((n>>5)&1)*512 + (((n>>3)&3)*16 + (d&15))*8 + (n&7)
// ---------------------------------------------------------------------------
__global__ __launch_bounds__(256) void gemm_qkv(
    const float* __restrict__ Wq, const float* __restrict__ bq,
    const float* __restrict__ Wk, const float* __restrict__ bk,
    const float* __restrict__ Wv, const float* __restrict__ bv,
    const ushort_t* __restrict__ xT,
    ushort_t* __restrict__ Qf, ushort_t* __restrict__ Kf, ushort_t* __restrict__ Vf)
{
    const int tid = threadIdx.x;
    const int w = tid >> 6, lane = tid & 63, l15 = lane & 15, lhi = lane >> 4;
    const int wm = w >> 1, wn = w & 1;
    const int m0 = blockIdx.y * 64 + wm * 32;
    const int n0 = blockIdx.x * 64 + wn * 32;
    const int z = blockIdx.z;

    const float* A    = (z == 0) ? Wq : (z == 1) ? Wk : Wv;
    const float* bias = (z == 0) ? bq : (z == 1) ? bk : bv;
    ushort_t* dst     = (z == 0) ? Qf : (z == 1) ? Kf : Vf;

    f32x4 acc[2][2];
    gemm_tile_body(A, xT, D_CH, m0, n0, l15, lhi, acc);

#pragma unroll
    for (int mf = 0; mf < 2; ++mf) {
#pragma unroll
        for (int r = 0; r < 4; ++r) {
            int m = m0 + mf * 16 + lhi * 4 + r;
            int head = m >> 6, dch = m & 63;
            float bi = bias[m];
#pragma unroll
            for (int nf = 0; nf < 2; ++nf) {
                int n = n0 + nf * 16 + l15;
                float v = acc[mf][nf][r] + bi;
                size_t idx;
                if (z < 2)
                    idx = (size_t)head * HSTRIDE + (size_t)(n >> 4) * 1024 + (dch >> 5) * 512
                        + (((dch >> 3) & 3) * 16 + (n & 15)) * 8 + (dch & 7);
                else
                    idx = (size_t)head * HSTRIDE + (size_t)(n >> 6) * 4096 + (dch >> 4) * 1024
                        + ((n >> 5) & 1) * 512 + (((n >> 3) & 3) * 16 + (dch & 15)) * 8 + (n & 7);
                dst[idx] = f2bf(v);
            }
        }
    }
}

// ---------------------------------------------------------------------------
// Generic MFMA GEMM for the MLP chain.
// out_mode: 0 = f32 C[m][n] (+resid);  3 = bf16 transposed Cu[n*M + m]
// ---------------------------------------------------------------------------
__global__ __launch_bounds__(256) void gemm_mfma(
    const float* __restrict__ A, const ushort_t* __restrict__ Bt,
    void* __restrict__ Cout, int M, int N, int K,
    const float* __restrict__ bias, const float* __restrict__ gamma,
    const float* __restrict__ beta, int relu, const float* __restrict__ resid,
    int out_mode)
{
    const int tid = threadIdx.x;
    const int w = tid >> 6, lane = tid & 63, l15 = lane & 15, lhi = lane >> 4;
    const int wm = w >> 1, wn = w & 1;
    const int m0 = blockIdx.y * 64 + wm * 32;
    const int n0 = blockIdx.x * 64 + wn * 32;

    f32x4 acc[2][2];
    gemm_tile_body(A, Bt, K, m0, n0, l15, lhi, acc);

    float* Cf = (float*)Cout;
    ushort_t* Cu = (ushort_t*)Cout;
#pragma unroll
    for (int mf = 0; mf < 2; ++mf) {
#pragma unroll
        for (int r = 0; r < 4; ++r) {
            int m = m0 + mf * 16 + lhi * 4 + r;
            float bi = bias[m];
            float sc = 1.0f, sh = 0.0f;
            if (gamma) { sc = gamma[m] * BN_RSQ; sh = beta[m]; }
#pragma unroll
            for (int nf = 0; nf < 2; ++nf) {
                int n = n0 + nf * 16 + l15;
                float v = acc[mf][nf][r] + bi;
                if (gamma) v = v * sc + sh;
                if (relu)  v = fmaxf(v, 0.0f);
                if (resid) v += resid[(size_t)m * N + n];
                if (out_mode == 0) Cf[(size_t)m * N + n] = v;
                else               Cu[(size_t)n * M + m] = f2bf(v);
            }
        }
    }
}

// ---------------------------------------------------------------------------
// One 64-key attention tile (swapped-operand, fragment-major inputs).
// scur holds this tile's mask (loaded one phase earlier); issues loads for
// tile ktnext into snxt. All global loads are lane-linear (coalesced).
// ---------------------------------------------------------------------------
__device__ __forceinline__ void attn_tile(
    int k0, int ktnext, const float* __restrict__ Sfw,
    const ushort_t* __restrict__ Kh, const ushort_t* __restrict__ Vh,
    const bf16x8& qf0, const bf16x8& qf1,
    f32x4 (&scur)[4], f32x4 (&snxt)[4], f32x4 (&macc)[4],
    float& mrun, float& lrun,
    ushort_t (* __restrict__ Pw)[72], int l15, int lhi, int lane)
{
    // issue next tile's S loads first (full phase of latency cover)
#pragma unroll
    for (int kb = 0; kb < 4; ++kb)
        snxt[kb] = *(const f32x4*)&Sfw[(size_t)ktnext * 4096 + kb * 256];

    // QK^T swapped: sacc[kb][r] = score[key=kb*16+lhi*4+r][q=l15]
    f32x4 sacc[4];
#pragma unroll
    for (int kb = 0; kb < 4; ++kb) {
        const ushort_t* kp = Kh + (size_t)((k0 >> 4) + kb) * 1024 + lane * 8;
        bf16x8 kf0 = *(const bf16x8*)kp;
        bf16x8 kf1 = *(const bf16x8*)(kp + 512);
        f32x4 z = (f32x4){0.f, 0.f, 0.f, 0.f};
        z = __builtin_amdgcn_mfma_f32_16x16x32_bf16(kf0, qf0, z, 0, 0, 0);
        z = __builtin_amdgcn_mfma_f32_16x16x32_bf16(kf1, qf1, z, 0, 0, 0);
        sacc[kb] = z;
    }

    // mask*scale; per-lane softmax over the tile's 64 keys
    float p_[4][4];
    float tmax = -3.0e38f;
#pragma unroll
    for (int kb = 0; kb < 4; ++kb)
#pragma unroll
        for (int r = 0; r < 4; ++r) {
            float sv = sacc[kb][r] * 0.125f * scur[kb][r];
            p_[kb][r] = sv;
            tmax = fmaxf(tmax, sv);
        }
    tmax = fmaxf(tmax, __shfl_xor(tmax, 16));
    tmax = fmaxf(tmax, __shfl_xor(tmax, 32));
    float mn = fmaxf(mrun, tmax);
    float cf = __expf(mrun - mn);
    mrun = mn;
    float tsum = 0.0f;
#pragma unroll
    for (int kb = 0; kb < 4; ++kb)
#pragma unroll
        for (int r = 0; r < 4; ++r) {
            p_[kb][r] = __expf(p_[kb][r] - mn);
            tsum += p_[kb][r];
        }
    tsum += __shfl_xor(tsum, 16);
    tsum += __shfl_xor(tsum, 32);
    lrun = lrun * cf + tsum;
#pragma unroll
    for (int db = 0; db < 4; ++db)
#pragma unroll
        for (int r = 0; r < 4; ++r) macc[db][r] *= cf;

    // P -> bf16 packed -> per-warp LDS [q][key]
#pragma unroll
    for (int kb = 0; kb < 4; ++kb) {
        *(unsigned*)&Pw[l15][kb * 16 + lhi * 4]     = pack2bf(p_[kb][0], p_[kb][1]);
        *(unsigned*)&Pw[l15][kb * 16 + lhi * 4 + 2] = pack2bf(p_[kb][2], p_[kb][3]);
    }
    // same-wave RAW through LDS; compiler inserts lgkmcnt wait

    // PV: mfma(A=V row=d, B=P col=q); V fragment-major loads
    const ushort_t* vb = Vh + (size_t)(k0 >> 6) * 4096 + lane * 8;
#pragma unroll
    for (int mm = 0; mm < 2; ++mm) {
        bf16x8 pf = *(const bf16x8*)&Pw[l15][mm * 32 + lhi * 8];
#pragma unroll
        for (int db = 0; db < 4; ++db) {
            bf16x8 vf = *(const bf16x8*)(vb + db * 1024 + mm * 512);
            macc[db] = __builtin_amdgcn_mfma_f32_16x16x32_bf16(vf, pf, macc[db], 0, 0, 0);
        }
    }
}

// ---------------------------------------------------------------------------
// MFMA flash attention: key-split 8, fragment-major inputs, 2-phase S stream.
// Block = (qtile 64, head, ksplit); 4 warps x 16 queries.
// ---------------------------------------------------------------------------
__global__ __launch_bounds__(256, 4) void attn_mfma(
    const ushort_t* __restrict__ Qf, const ushort_t* __restrict__ Kf,
    const ushort_t* __restrict__ Vf, const float* __restrict__ Sf,
    ushort_t* __restrict__ pacc, float* __restrict__ pm, float* __restrict__ pl)
{
    __shared__ __align__(16) ushort_t P_lds[4][16][72];

    const int tid  = threadIdx.x;
    const int w    = tid >> 6;
    const int lane = tid & 63;
    const int l15  = lane & 15;
    const int lhi  = lane >> 4;
    const int h    = blockIdx.y;
    const int ks   = blockIdx.z;
    const int q0   = blockIdx.x * 64 + w * 16;
    const int kbase = ks * KCHUNK, kend = kbase + KCHUNK;

    const ushort_t* Kh = Kf + (size_t)h * HSTRIDE;
    const ushort_t* Vh = Vf + (size_t)h * HSTRIDE;
    const float* Sfw = Sf + (size_t)blockIdx.x * 64 * 4096 + w * 1024 + lane * 4;
    ushort_t (* __restrict__ Pw)[72] = P_lds[w];

    bf16x8 qf0, qf1;
    {
        const ushort_t* qp = Qf + (size_t)h * HSTRIDE + (size_t)(q0 >> 4) * 1024 + lane * 8;
        qf0 = *(const bf16x8*)qp;
        qf1 = *(const bf16x8*)(qp + 512);
    }

    f32x4 macc[4];
#pragma unroll
    for (int db = 0; db < 4; ++db) macc[db] = (f32x4){0.f, 0.f, 0.f, 0.f};
    float mrun = -3.0e38f, lrun = 0.0f;

    // preload S tile 0 into sA
    f32x4 sA[4], sB[4];
#pragma unroll
    for (int kb = 0; kb < 4; ++kb)
        sA[kb] = *(const f32x4*)&Sfw[(size_t)(kbase >> 6) * 4096 + kb * 256];

    // KCHUNK=512 -> 4 pair-iterations of 2 tiles (static A/B phases)
    for (int k0 = kbase; k0 < kend; k0 += 128) {
        const int kt1 = (k0 + 64) >> 6;
        const int kt2 = ((k0 + 128 < kend) ? k0 + 128 : kbase) >> 6;
        attn_tile(k0,      kt1, Sfw, Kh, Vh, qf0, qf1, sA, sB, macc, mrun, lrun, Pw, l15, lhi, lane);
        attn_tile(k0 + 64, kt2, Sfw, Kh, Vh, qf0, qf1, sB, sA, macc, mrun, lrun, Pw, l15, lhi, lane);
    }

    // store unnormalized partials
    const size_t pb = ((size_t)ks * NHEAD + h) * NPTS;
    ushort_t* prow = pacc + (pb + q0 + l15) * DHEAD;
#pragma unroll
    for (int db = 0; db < 4; ++db) {
        *(unsigned*)&prow[db * 16 + lhi * 4]     = pack2bf(macc[db][0], macc[db][1]);
        *(unsigned*)&prow[db * 16 + lhi * 4 + 2] = pack2bf(macc[db][2], macc[db][3]);
    }
    if (lane < 16) {
        pm[pb + q0 + lane] = mrun;
        pl[pb + q0 + lane] = lrun;
    }
}

// ---------------------------------------------------------------------------
// Merge KSPLIT partials -> msgT [N][256] bf16.
// ---------------------------------------------------------------------------
__global__ __launch_bounds__(256) void attn_merge(
    const ushort_t* __restrict__ pacc, const float* __restrict__ pm,
    const float* __restrict__ pl, ushort_t* __restrict__ msgT)
{
    const int h = blockIdx.y;
    const int q = blockIdx.x * 64 + (threadIdx.x >> 2);
    const int d0 = (threadIdx.x & 3) * 16;

    float m[KSPLIT], l[KSPLIT];
#pragma unroll
    for (int ks = 0; ks < KSPLIT; ++ks) {
        size_t pb = ((size_t)ks * NHEAD + h) * NPTS + q;
        m[ks] = pm[pb];
        l[ks] = pl[pb];
    }
    float ms = m[0];
#pragma unroll
    for (int ks = 1; ks < KSPLIT; ++ks) ms = fmaxf(ms, m[ks]);
    float wgt[KSPLIT], ls = 0.0f;
#pragma unroll
    for (int ks = 0; ks < KSPLIT; ++ks) {
        wgt[ks] = __expf(m[ks] - ms);
        ls += wgt[ks] * l[ks];
    }
    float inv = 1.0f / ls;

    float out[16];
#pragma unroll
    for (int j = 0; j < 16; ++j) out[j] = 0.0f;
#pragma unroll
    for (int ks = 0; ks < KSPLIT; ++ks) {
        const ushort_t* ap = pacc + (((size_t)ks * NHEAD + h) * NPTS + q) * DHEAD + d0;
        bf16x8 v0 = *(const bf16x8*)ap;
        bf16x8 v1 = *(const bf16x8*)(ap + 8);
#pragma unroll
        for (int j = 0; j < 8; ++j) {
            out[j]     += wgt[ks] * bf2f((ushort_t)v0[j]);
            out[8 + j] += wgt[ks] * bf2f((ushort_t)v1[j]);
        }
    }
    bf16x8 o0, o1;
#pragma unroll
    for (int j = 0; j < 8; ++j) {
        o0[j] = (short)f2bf(out[j] * inv);
        o1[j] = (short)f2bf(out[8 + j] * inv);
    }
    ushort_t* op = msgT + (size_t)q * D_CH + h * DHEAD + d0;
    *(bf16x8*)op = o0;
    *(bf16x8*)(op + 8) = o1;
}

// ---------------------------------------------------------------------------
extern "C" void kernel_launch(void* const* d_in, const int* in_sizes, int n_in,
                              void* d_out, int out_size, void* d_ws, size_t ws_size,
                              hipStream_t stream) {
    const float* x  = (const float*)d_in[0];
    const float* S  = (const float*)d_in[1];
    const float* Wq = (const float*)d_in[2];
    const float* bq = (const float*)d_in[3];
    const float* Wk = (const float*)d_in[4];
    const float* bk = (const float*)d_in[5];
    const float* Wv = (const float*)d_in[6];
    const float* bv = (const float*)d_in[7];
    const float* W1 = (const float*)d_in[8];
    const float* b1 = (const float*)d_in[9];
    const float* g1 = (const float*)d_in[10];
    const float* be1= (const float*)d_in[11];
    const float* W2 = (const float*)d_in[12];
    const float* b2 = (const float*)d_in[13];
    const float* g2 = (const float*)d_in[14];
    const float* be2= (const float*)d_in[15];
    const float* W3 = (const float*)d_in[16];
    const float* b3 = (const float*)d_in[17];

    char* ws = (char*)d_ws;
    const size_t MB = 1024 * 1024;
    // Sf occupies 0..64MB; xT (dead after gemm_qkv) overlaps its head.
    float*    Sf   = (float*)   (ws);                        // 64 MB tile-major mask
    ushort_t* xT   = (ushort_t*)(ws);                        // 2 MB (consumed before prep_mask)
    ushort_t* Qf   = (ushort_t*)(ws + 64 * MB);              // 2 MB
    ushort_t* Kf   = (ushort_t*)(ws + 66 * MB);              // 2 MB
    ushort_t* Vf   = (ushort_t*)(ws + 68 * MB);              // 2 MB
    ushort_t* pacc = (ushort_t*)(ws + 70 * MB);              // 16 MB
    float*    pm   = (float*)   (ws + 86 * MB);              // 512 KB
    float*    pl   = (float*)   (ws + 86 * MB + 524288);     // 512 KB
    ushort_t* msgT = (ushort_t*)(ws + 87 * MB);              // 2 MB
    ushort_t* h1T  = (ushort_t*)(ws + 89 * MB);              // 1 MB
    ushort_t* h2T  = (ushort_t*)(ws + 90 * MB);              // 1 MB

    transpose_cast<<<dim3(64, 4), 256, 0, stream>>>(x, xT);
    gemm_qkv<<<dim3(64, 4, 3), 256, 0, stream>>>(Wq, bq, Wk, bk, Wv, bv, xT, Qf, Kf, Vf);
    prep_mask<<<dim3(64, 64), 256, 0, stream>>>(S, Sf);

    attn_mfma<<<dim3(64, NHEAD, KSPLIT), 256, 0, stream>>>(Qf, Kf, Vf, Sf, pacc, pm, pl);
    attn_merge<<<dim3(64, NHEAD), 256, 0, stream>>>(pacc, pm, pl, msgT);

    gemm_mfma<<<dim3(64, 2), 256, 0, stream>>>(W1, msgT, h1T, 128, NPTS, 256, b1, g1, be1, 1, nullptr, 3);
    gemm_mfma<<<dim3(64, 2), 256, 0, stream>>>(W2, h1T, h2T, 128, NPTS, 128, b2, g2, be2, 1, nullptr, 3);
    gemm_mfma<<<dim3(64, 4), 256, 0, stream>>>(W3, h2T, d_out, 256, NPTS, 128, b3, nullptr, nullptr, 0, x, 0);
}